// Round 1
// baseline (386.453 us; speedup 1.0000x reference)
//
#include <hip/hip_runtime.h>

typedef short bf16x8 __attribute__((ext_vector_type(8)));
typedef float f32x4 __attribute__((ext_vector_type(4)));
typedef unsigned short u16;

__device__ __forceinline__ u16 f2bf(float f) {
    unsigned u = __builtin_bit_cast(unsigned, f);
    return (u16)((u + 0x7fffu + ((u >> 16) & 1u)) >> 16);   // RNE
}

// ---------------- kernel 1: pad + convert x to bf16 --------------------------
// xpad[b][r][d], r in [0,8192): rows < 4096 are zeros (causal mask), 4096+t = x[b,t,:]
__global__ void k_pad_x(const float* __restrict__ x, u16* __restrict__ xpad) {
    int gid = blockIdx.x * 256 + threadIdx.x;        // handles 4 elems
    int b   = gid >> 17;                             // 2^17 float4-groups per batch
    int rem = gid & 131071;
    int r   = rem >> 4;
    int c4  = rem & 15;
    u16 o0 = 0, o1 = 0, o2 = 0, o3 = 0;
    if (r >= 4096) {
        const f32x4 v = *(const f32x4*)(x + ((b << 12) + (r - 4096)) * 64 + c4 * 4);
        o0 = f2bf(v.x); o1 = f2bf(v.y); o2 = f2bf(v.z); o3 = f2bf(v.w);
    }
    u16* p = xpad + ((b << 13) + r) * 64 + c4 * 4;
    p[0] = o0; p[1] = o1; p[2] = o2; p[3] = o3;
}

// ---------------- kernel 2: build Wtot[s][o][d] (bf16) -----------------------
// W[s][o][d] = sum_k phi[s,k]*(Mp[k,d,o] + sgn(s)*Mm[k,d,o])  (+ M[o,d,s] for s<3)
// block: 64 s-values (sb) x 4 o-values (oc). grid = 64*16 = 1024 blocks.
__global__ __launch_bounds__(256)
void k_build_w(const float* __restrict__ phi, const float* __restrict__ Mp,
               const float* __restrict__ Mm, const float* __restrict__ Mar,
               u16* __restrict__ wg) {
    __shared__ float phis[64 * 40];
    __shared__ float ApL[160 * 66];    // [(k*4+oloc)*66 + d]
    __shared__ float AmL[160 * 66];
    const int sb = blockIdx.x >> 4, oc = blockIdx.x & 15;
    const int s0 = sb * 64, o0 = oc * 4;
    const int tid = threadIdx.x;

    for (int f = tid; f < 2560; f += 256) phis[f] = phi[s0 * 40 + f];
    for (int f = tid; f < 2560; f += 256) {
        int k = f >> 6, d = f & 63;
        const f32x4 p = *(const f32x4*)(Mp + k * 4096 + d * 64 + o0);
        const f32x4 m = *(const f32x4*)(Mm + k * 4096 + d * 64 + o0);
        float pp[4] = {p.x, p.y, p.z, p.w};
        float mm[4] = {m.x, m.y, m.z, m.w};
        #pragma unroll
        for (int c = 0; c < 4; ++c) {
            ApL[(k * 4 + c) * 66 + d] = pp[c] + mm[c];
            AmL[(k * 4 + c) * 66 + d] = pp[c] - mm[c];
        }
    }
    __syncthreads();

    const int oloc = tid >> 6, d = tid & 63;
    const int o = o0 + oloc;
    const int qg = o * 64 + d;                      // = o0*64 + tid
    float ap[40], am[40];
    #pragma unroll
    for (int k = 0; k < 40; ++k) {
        ap[k] = ApL[(k * 4 + oloc) * 66 + d];
        am[k] = AmL[(k * 4 + oloc) * 66 + d];
    }
    for (int j = 0; j < 64; ++j) {
        const int s = s0 + j;
        const float* ph = phis + j * 40;
        float acc = 0.f;
        if ((s & 1) == 0) {
            #pragma unroll
            for (int k = 0; k < 40; ++k) acc += ph[k] * ap[k];
        } else {
            #pragma unroll
            for (int k = 0; k < 40; ++k) acc += ph[k] * am[k];
        }
        if (s < 3) acc += Mar[o * 192 + d * 3 + s];   // fold AR term into W[0..2]
        wg[s * 4096 + qg] = f2bf(acc);
    }
}

// ---------------- kernel 3: triangular conv-GEMM via MFMA --------------------
// out[b,t,o] += sum_{s in chunk} sum_d xpad[b][4096+t-s][d] * Wtot[s][o][d]
// Tile: I = 128 t-rows (both batches -> M=256), J = 64 s-values. Active: J<=2I+1.
__global__ __launch_bounds__(256, 2)
void k_spectral(const u16* __restrict__ xpad, const u16* __restrict__ wg,
                float* __restrict__ out) {
    const int I = blockIdx.x, J = blockIdx.y;
    if (J > 2 * I + 1) return;
    const int t0 = I << 7, s0 = J << 6;

    __shared__ __align__(16) u16 xs[2 * 192 * 64];   // swizzled x window, 48KB
    __shared__ __align__(16) u16 wsm[2 * 64 * 64];   // double-buffered W tile, 16KB

    const int tid = threadIdx.x;
    const int lane = tid & 63, w = tid >> 6;
    const int m15 = lane & 15, q4 = lane >> 4;
    const int wbase = t0 - s0 - 63;

    // ---- stage x window (rows t-s for t in [t0,t0+128), s in [s0,s0+64)) ----
    #pragma unroll
    for (int b = 0; b < 2; ++b) {
        #pragma unroll
        for (int ii = 0; ii < 6; ++ii) {
            int f = tid + ii * 256;                  // 0..1535
            int r = f >> 3, c = f & 7;
            int g = 4096 + wbase + r;
            if (g > 8191) g = 8191;                  // row 191 never read
            bf16x8 v = *(const bf16x8*)(xpad + ((b << 13) + g) * 64 + c * 8);
            *(bf16x8*)(xs + ((b * 192 + r) * 8 + (c ^ (r & 7))) * 8) = v;
        }
    }
    // prefetch W[s0]
    bf16x8 pre0 = *(const bf16x8*)(wg + s0 * 4096 + (tid * 2) * 8);
    bf16x8 pre1 = *(const bf16x8*)(wg + s0 * 4096 + (tid * 2 + 1) * 8);

    f32x4 acc[4][4];
    #pragma unroll
    for (int mt = 0; mt < 4; ++mt)
        #pragma unroll
        for (int nt = 0; nt < 4; ++nt)
            acc[mt][nt] = (f32x4){0.f, 0.f, 0.f, 0.f};

    const int batch = w >> 1, tb_loc = (w & 1) << 6;
    const int fo0 = (tid * 2) >> 3, fc0 = (tid * 2) & 7;
    const int fo1 = (tid * 2 + 1) >> 3, fc1 = (tid * 2 + 1) & 7;

    #pragma unroll 2
    for (int ds = 0; ds < 64; ++ds) {
        const int bufo = (ds & 1) * 4096;
        // write prefetched W[s0+ds] tile to LDS (vmcnt wait was hidden by prior compute)
        *(bf16x8*)(wsm + bufo + (fo0 * 8 + (fc0 ^ (fo0 & 7))) * 8) = pre0;
        *(bf16x8*)(wsm + bufo + (fo1 * 8 + (fc1 ^ (fo1 & 7))) * 8) = pre1;
        __syncthreads();
        // issue next prefetch AFTER the barrier so the barrier never drains a fresh load
        if (ds < 63) {
            const u16* wp = wg + (s0 + ds + 1) * 4096;
            pre0 = *(const bf16x8*)(wp + (tid * 2) * 8);
            pre1 = *(const bf16x8*)(wp + (tid * 2 + 1) * 8);
        }
        // fragment loads (xor-swizzled, conflict-free ds_read_b128)
        bf16x8 af[4][2], bfr[4][2];
        const int rb = tb_loc + m15 + 63 - ds;       // sliding window row
        #pragma unroll
        for (int mt = 0; mt < 4; ++mt) {
            int r = rb + mt * 16;
            #pragma unroll
            for (int ks = 0; ks < 2; ++ks) {
                int c = (ks * 4 + q4) ^ (r & 7);
                af[mt][ks] = *(const bf16x8*)(xs + ((batch * 192 + r) * 8 + c) * 8);
            }
        }
        #pragma unroll
        for (int nt = 0; nt < 4; ++nt) {
            int o = nt * 16 + m15;
            #pragma unroll
            for (int ks = 0; ks < 2; ++ks) {
                int c = (ks * 4 + q4) ^ (o & 7);
                bfr[nt][ks] = *(const bf16x8*)(wsm + bufo + (o * 8 + c) * 8);
            }
        }
        #pragma unroll
        for (int mt = 0; mt < 4; ++mt)
            #pragma unroll
            for (int nt = 0; nt < 4; ++nt) {
                acc[mt][nt] = __builtin_amdgcn_mfma_f32_16x16x32_bf16(
                    af[mt][0], bfr[nt][0], acc[mt][nt], 0, 0, 0);
                acc[mt][nt] = __builtin_amdgcn_mfma_f32_16x16x32_bf16(
                    af[mt][1], bfr[nt][1], acc[mt][nt], 0, 0, 0);
            }
    }

    // ---- epilogue: fp32 atomic accumulation (<=64 partials per element) ----
    const int tb = t0 + tb_loc;
    #pragma unroll
    for (int mt = 0; mt < 4; ++mt) {
        int t = tb + mt * 16 + q4 * 4;
        #pragma unroll
        for (int nt = 0; nt < 4; ++nt) {
            int o = nt * 16 + m15;
            float* op = out + ((batch << 12) + t) * 64 + o;
            #pragma unroll
            for (int r = 0; r < 4; ++r)
                atomicAdd(op + r * 64, acc[mt][nt][r]);
        }
    }
}

// ---------------------------------------------------------------------------
extern "C" void kernel_launch(void* const* d_in, const int* in_sizes, int n_in,
                              void* d_out, int out_size, void* d_ws, size_t ws_size,
                              hipStream_t stream) {
    const float* x   = (const float*)d_in[0];   // (2, 4096, 64)
    const float* phi = (const float*)d_in[1];   // (4096, 40)
    const float* M   = (const float*)d_in[2];   // (64, 64, 3)
    const float* Mp  = (const float*)d_in[3];   // (40, 64, 64)
    const float* Mm  = (const float*)d_in[4];   // (40, 64, 64)
    float* out = (float*)d_out;                 // (2, 4096, 64)

    // workspace: xpad 2*8192*64*2B = 2 MiB, Wtot 4096*64*64*2B = 32 MiB
    u16* xpad = (u16*)d_ws;
    u16* wg   = (u16*)((char*)d_ws + 2097152);

    k_pad_x<<<1024, 256, 0, stream>>>(x, xpad);
    k_build_w<<<1024, 256, 0, stream>>>(phi, Mp, Mm, M, wg);
    hipMemsetAsync(d_out, 0, 2 * 4096 * 64 * sizeof(float), stream);
    dim3 grid(32, 64);
    k_spectral<<<grid, 256, 0, stream>>>(xpad, wg, out);
}